// Round 6
// baseline (888.728 us; speedup 1.0000x reference)
//
#include <hip/hip_runtime.h>
#include <math.h>

#define NN 100000
#define NE 3200000
#define BW 128          // nodes per bucket
#define BSH 7           // log2(BW)
#define NB 782          // ceil(NN / BW)
#define EPB 8192        // edges per block in hist/bin kernels
#define NBLKH ((NE + EPB - 1) / EPB)   // 391

__device__ __forceinline__ float lrelu(float v) { return v >= 0.f ? v : 0.2f * v; }

// ---------------- CSR-bucket build: hist -> scan -> offsets -> scatter ----------------

__global__ __launch_bounds__(256) void k_bhist(const int* __restrict__ dst,
    unsigned* __restrict__ btot, unsigned* __restrict__ hcnt) {
  __shared__ unsigned lh[NB];
  int tid = threadIdx.x;
  for (int i = tid; i < NB; i += 256) lh[i] = 0;
  __syncthreads();
  int base = blockIdx.x * EPB;
  int end = min(base + EPB, NE);
  for (int e = base + tid * 4; e < end; e += 1024) {
    int4 d4 = *(const int4*)(dst + e);
    atomicAdd(&lh[((unsigned)d4.x) >> BSH], 1u);
    atomicAdd(&lh[((unsigned)d4.y) >> BSH], 1u);
    atomicAdd(&lh[((unsigned)d4.z) >> BSH], 1u);
    atomicAdd(&lh[((unsigned)d4.w) >> BSH], 1u);
  }
  __syncthreads();
  unsigned* row = hcnt + (size_t)blockIdx.x * NB;
  for (int i = tid; i < NB; i += 256) {
    unsigned c = lh[i];
    row[i] = c;
    if (c) atomicAdd(&btot[i], c);
  }
}

__global__ __launch_bounds__(256) void k_bscan(const unsigned* __restrict__ btot,
                                               unsigned* __restrict__ bstart) {
  __shared__ unsigned sm[256];
  int tid = threadIdx.x;
  int base = tid * 4;
  unsigned c[4];
  #pragma unroll
  for (int k = 0; k < 4; ++k) c[k] = (base + k < NB) ? btot[base + k] : 0u;
  unsigned s = c[0] + c[1] + c[2] + c[3];
  sm[tid] = s;
  __syncthreads();
  for (int off = 1; off < 256; off <<= 1) {
    unsigned u = (tid >= off) ? sm[tid - off] : 0u;
    __syncthreads();
    sm[tid] += u;
    __syncthreads();
  }
  unsigned run = sm[tid] - s;
  #pragma unroll
  for (int k = 0; k < 4; ++k) {
    if (base + k < NB) bstart[base + k] = run;
    run += c[k];
  }
  if (tid == 255) bstart[NB] = sm[255];
}

// in-place: hcnt[blk][b] (count) -> global scatter offset for (blk, b)
__global__ __launch_bounds__(256) void k_boff(const unsigned* __restrict__ bstart,
                                              unsigned* __restrict__ hcnt) {
  int b = blockIdx.x * 256 + threadIdx.x;
  if (b >= NB) return;
  unsigned run = bstart[b];
  for (int blk = 0; blk < NBLKH; ++blk) {
    size_t idx = (size_t)blk * NB + b;
    unsigned c = hcnt[idx];
    hcnt[idx] = run;
    run += c;
  }
}

__global__ __launch_bounds__(256) void k_bin(const int* __restrict__ src,
    const int* __restrict__ dst, const unsigned* __restrict__ hcnt,
    unsigned* __restrict__ abuf) {
  __shared__ unsigned gb[NB];
  __shared__ unsigned lcur[NB];
  int tid = threadIdx.x;
  const unsigned* row = hcnt + (size_t)blockIdx.x * NB;
  for (int i = tid; i < NB; i += 256) { gb[i] = row[i]; lcur[i] = 0; }
  __syncthreads();
  int base = blockIdx.x * EPB;
  int end = min(base + EPB, NE);
  for (int e = base + tid * 4; e < end; e += 1024) {
    int4 d4 = *(const int4*)(dst + e);
    int4 s4 = *(const int4*)(src + e);
    #pragma unroll
    for (int k = 0; k < 4; ++k) {
      unsigned d = (unsigned)(&d4.x)[k];
      unsigned s = (unsigned)(&s4.x)[k];
      unsigned b = d >> BSH;
      unsigned p = gb[b] + atomicAdd(&lcur[b], 1u);
      abuf[p] = ((d & (BW - 1)) << 17) | s;   // src < 2^17
    }
  }
}

// ---------------- K1: [xl1 | xr1] = x @ [W1l | W1r] ----------------

__global__ __launch_bounds__(256) void k1_lin1(const float* __restrict__ x,
    const float* __restrict__ W1l, const float* __restrict__ W1r,
    float* __restrict__ xl1, float* __restrict__ xr1) {
  __shared__ float lw[256][32];
  int tid = threadIdx.x;
  for (int i = tid; i < 256 * 16; i += 256) {
    int k = i >> 4, c = i & 15;
    lw[k][c]      = W1l[i];
    lw[k][16 + c] = W1r[i];
  }
  __syncthreads();
  int row = blockIdx.x * 256 + tid;
  if (row >= NN) return;
  const float4* xr4 = (const float4*)(x + (size_t)row * 256);

  float acc[32];
  #pragma unroll
  for (int c = 0; c < 32; ++c) acc[c] = 0.f;

  float4 va = xr4[0], vb = xr4[1];
  for (int k4 = 0; k4 < 64; k4 += 2) {
    float4 vc = xr4[(k4 + 2) & 63];
    float4 vd = xr4[(k4 + 3) & 63];
    #pragma unroll
    for (int half = 0; half < 2; ++half) {
      float4 v = half ? vb : va;
      int kb = (k4 + half) * 4;
      #pragma unroll
      for (int kk = 0; kk < 4; ++kk) {
        float xk = (&v.x)[kk];
        const float4* wrow = (const float4*)&lw[kb + kk][0];
        #pragma unroll
        for (int q = 0; q < 8; ++q) {
          float4 w = wrow[q];
          acc[q * 4 + 0] = fmaf(xk, w.x, acc[q * 4 + 0]);
          acc[q * 4 + 1] = fmaf(xk, w.y, acc[q * 4 + 1]);
          acc[q * 4 + 2] = fmaf(xk, w.z, acc[q * 4 + 2]);
          acc[q * 4 + 3] = fmaf(xk, w.w, acc[q * 4 + 3]);
        }
      }
    }
    va = vc; vb = vd;
  }
  float4* ol = (float4*)(xl1 + (size_t)row * 16);
  float4* orr = (float4*)(xr1 + (size_t)row * 16);
  #pragma unroll
  for (int q = 0; q < 4; ++q) {
    ol[q]  = make_float4(acc[q*4+0], acc[q*4+1], acc[q*4+2], acc[q*4+3]);
    orr[q] = make_float4(acc[16+q*4+0], acc[16+q*4+1], acc[16+q*4+2], acc[16+q*4+3]);
  }
}

// ---------------- Layer 1: block-per-bucket, edge-parallel, LDS accumulators ----------------
// epilogue fuses elu(+b1) and both 16->8 transforms

__global__ __launch_bounds__(256) void k_l1b(const float* __restrict__ xl1,
    const float* __restrict__ xr1, const float* __restrict__ a1,
    const float* __restrict__ b1, const float* __restrict__ W2l,
    const float* __restrict__ W2r, const unsigned* __restrict__ bstart,
    const unsigned* __restrict__ abuf,
    float* __restrict__ xl2, float* __restrict__ xr2) {
  __shared__ float accs[16][BW];   // channel-major: bank = node%32
  __shared__ float dens[4][BW];
  __shared__ float w2[16][16];     // cols 0..7 W2l, 8..15 W2r
  int tid = threadIdx.x;
  int b = blockIdx.x;
  for (int i = tid; i < 16 * BW; i += 256) accs[i >> BSH][i & (BW - 1)] = 0.f;
  for (int i = tid; i < 4 * BW; i += 256) dens[i >> BSH][i & (BW - 1)] = 0.f;
  if (tid < 128) {
    int k = tid >> 3, c = tid & 7;
    w2[k][c]     = W2l[tid];
    w2[k][8 + c] = W2r[tid];
  }
  __syncthreads();

  unsigned s0 = bstart[b], s1 = bstart[b + 1];
  int node0 = b * BW;
  float a1r[16];
  #pragma unroll
  for (int c = 0; c < 16; ++c) a1r[c] = a1[c];

  for (unsigned e = s0 + tid; e < s1; e += 256) {
    unsigned v = abuf[e];
    unsigned s = v & 0x1FFFFu;
    unsigned dloc = (v >> 17) & (BW - 1);
    const float4* xlp = (const float4*)(xl1 + (size_t)s * 16);
    const float4* xrp = (const float4*)(xr1 + (size_t)(node0 + dloc) * 16);
    #pragma unroll
    for (int h = 0; h < 4; ++h) {
      float4 xl = xlp[h];
      float4 xr = xrp[h];
      float lg = lrelu(xl.x + xr.x) * a1r[h*4+0] + lrelu(xl.y + xr.y) * a1r[h*4+1]
               + lrelu(xl.z + xr.z) * a1r[h*4+2] + lrelu(xl.w + xr.w) * a1r[h*4+3];
      float p = __expf(lg);
      atomicAdd(&dens[h][dloc], p);
      atomicAdd(&accs[h*4+0][dloc], p * xl.x);
      atomicAdd(&accs[h*4+1][dloc], p * xl.y);
      atomicAdd(&accs[h*4+2][dloc], p * xl.z);
      atomicAdd(&accs[h*4+3][dloc], p * xl.w);
    }
  }
  __syncthreads();

  if (tid < BW) {
    int n = node0 + tid;
    if (n < NN) {
      float hh[16];
      #pragma unroll
      for (int h = 0; h < 4; ++h) {
        float inv = 1.f / (dens[h][tid] + 1e-16f);
        #pragma unroll
        for (int c = 0; c < 4; ++c) {
          float v = fmaf(accs[h*4+c][tid], inv, b1[h*4+c]);
          hh[h*4+c] = v > 0.f ? v : __expf(v) - 1.f;
        }
      }
      float ol[8], orr[8];
      #pragma unroll
      for (int j = 0; j < 8; ++j) { ol[j] = 0.f; orr[j] = 0.f; }
      #pragma unroll
      for (int k = 0; k < 16; ++k) {
        float hv = hh[k];
        #pragma unroll
        for (int j = 0; j < 8; ++j) {
          ol[j]  = fmaf(hv, w2[k][j], ol[j]);
          orr[j] = fmaf(hv, w2[k][8 + j], orr[j]);
        }
      }
      *(float4*)(xl2 + (size_t)n * 8)     = make_float4(ol[0], ol[1], ol[2], ol[3]);
      *(float4*)(xl2 + (size_t)n * 8 + 4) = make_float4(ol[4], ol[5], ol[6], ol[7]);
      *(float4*)(xr2 + (size_t)n * 8)     = make_float4(orr[0], orr[1], orr[2], orr[3]);
      *(float4*)(xr2 + (size_t)n * 8 + 4) = make_float4(orr[4], orr[5], orr[6], orr[7]);
    }
  }
}

// ---------------- Layer 2: block-per-bucket, edge-parallel, fused sigmoid ----------------

__global__ __launch_bounds__(256) void k_l2b(const float* __restrict__ xl2,
    const float* __restrict__ xr2, const float* __restrict__ a2,
    const float* __restrict__ b2, const unsigned* __restrict__ bstart,
    const unsigned* __restrict__ abuf, float* __restrict__ out) {
  __shared__ float accs[8][BW];
  __shared__ float dens[BW];
  int tid = threadIdx.x;
  int b = blockIdx.x;
  for (int i = tid; i < 8 * BW; i += 256) accs[i >> BSH][i & (BW - 1)] = 0.f;
  if (tid < BW) dens[tid] = 0.f;
  __syncthreads();

  unsigned s0 = bstart[b], s1 = bstart[b + 1];
  int node0 = b * BW;
  float a2r[8];
  #pragma unroll
  for (int c = 0; c < 8; ++c) a2r[c] = a2[c];

  for (unsigned e = s0 + tid; e < s1; e += 256) {
    unsigned v = abuf[e];
    unsigned s = v & 0x1FFFFu;
    unsigned dloc = (v >> 17) & (BW - 1);
    const float4* xlp = (const float4*)(xl2 + (size_t)s * 8);
    const float4* xrp = (const float4*)(xr2 + (size_t)(node0 + dloc) * 8);
    float4 l0 = xlp[0], l1v = xlp[1];
    float4 r0 = xrp[0], r1v = xrp[1];
    float lg = lrelu(l0.x + r0.x) * a2r[0] + lrelu(l0.y + r0.y) * a2r[1]
             + lrelu(l0.z + r0.z) * a2r[2] + lrelu(l0.w + r0.w) * a2r[3]
             + lrelu(l1v.x + r1v.x) * a2r[4] + lrelu(l1v.y + r1v.y) * a2r[5]
             + lrelu(l1v.z + r1v.z) * a2r[6] + lrelu(l1v.w + r1v.w) * a2r[7];
    float p = __expf(lg);
    atomicAdd(&dens[dloc], p);
    atomicAdd(&accs[0][dloc], p * l0.x);
    atomicAdd(&accs[1][dloc], p * l0.y);
    atomicAdd(&accs[2][dloc], p * l0.z);
    atomicAdd(&accs[3][dloc], p * l0.w);
    atomicAdd(&accs[4][dloc], p * l1v.x);
    atomicAdd(&accs[5][dloc], p * l1v.y);
    atomicAdd(&accs[6][dloc], p * l1v.z);
    atomicAdd(&accs[7][dloc], p * l1v.w);
  }
  __syncthreads();

  if (tid < BW) {
    int n = node0 + tid;
    if (n < NN) {
      float inv = 1.f / (dens[tid] + 1e-16f);
      float o[8];
      #pragma unroll
      for (int c = 0; c < 8; ++c) {
        float v = fmaf(accs[c][tid], inv, b2[c]);
        o[c] = 1.f / (1.f + __expf(-v));
      }
      *(float4*)(out + (size_t)n * 8)     = make_float4(o[0], o[1], o[2], o[3]);
      *(float4*)(out + (size_t)n * 8 + 4) = make_float4(o[4], o[5], o[6], o[7]);
    }
  }
}

// ---------------- launcher ----------------

extern "C" void kernel_launch(void* const* d_in, const int* in_sizes, int n_in,
                              void* d_out, int out_size, void* d_ws, size_t ws_size,
                              hipStream_t stream) {
  const float* x   = (const float*)d_in[0];
  const int*   ei  = (const int*)d_in[1];
  const float* W1l = (const float*)d_in[2];
  const float* W1r = (const float*)d_in[3];
  const float* a1  = (const float*)d_in[4];
  const float* b1  = (const float*)d_in[5];
  const float* W2l = (const float*)d_in[6];
  const float* W2r = (const float*)d_in[7];
  const float* a2  = (const float*)d_in[8];
  const float* b2  = (const float*)d_in[9];
  const int* src = ei;
  const int* dst = ei + NE;

  char* ws = (char*)d_ws;
  size_t off = 0;
  auto alloc = [&](size_t bytes) { void* p = (void*)(ws + off); off += (bytes + 255) & ~(size_t)255; return p; };
  unsigned* btot   = (unsigned*)alloc((size_t)NB * 4);
  unsigned* bstart = (unsigned*)alloc((size_t)(NB + 1) * 4);
  unsigned* hcnt   = (unsigned*)alloc((size_t)NBLKH * NB * 4);   // 1.22 MB
  unsigned* abuf   = (unsigned*)alloc((size_t)NE * 4);           // 12.8 MB
  float*    xl1    = (float*)alloc((size_t)NN * 16 * 4);
  float*    xr1    = (float*)alloc((size_t)NN * 16 * 4);
  float*    xl2    = (float*)alloc((size_t)NN * 8 * 4);
  float*    xr2    = (float*)alloc((size_t)NN * 8 * 4);

  hipMemsetAsync(btot, 0, (size_t)NB * 4, stream);

  k_bhist<<<NBLKH, 256, 0, stream>>>(dst, btot, hcnt);
  k_bscan<<<1, 256, 0, stream>>>(btot, bstart);
  k_boff <<<(NB + 255) / 256, 256, 0, stream>>>(bstart, hcnt);
  k_bin  <<<NBLKH, 256, 0, stream>>>(src, dst, hcnt, abuf);

  k1_lin1<<<(NN + 255) / 256, 256, 0, stream>>>(x, W1l, W1r, xl1, xr1);

  k_l1b<<<NB, 256, 0, stream>>>(xl1, xr1, a1, b1, W2l, W2r, bstart, abuf, xl2, xr2);
  k_l2b<<<NB, 256, 0, stream>>>(xl2, xr2, a2, b2, bstart, abuf, (float*)d_out);
}